// Round 1
// 675.827 us; speedup vs baseline: 1.0290x; 1.0290x over previous
//
#include <hip/hip_runtime.h>

typedef _Float16 f16;
typedef _Float16 h2 __attribute__((ext_vector_type(2)));
typedef _Float16 f16x8 __attribute__((ext_vector_type(8)));
typedef float    f32x4 __attribute__((ext_vector_type(4)));
typedef unsigned int u32;
typedef u32 u32x4 __attribute__((ext_vector_type(4)));

#define CCH 66
#define LLEN 100
#define BSZ 4096
#define NPAIR 2048              // batch pairs (2 batches per thread, packed in h2)
#define NPAD 2048
#define NOUT 1936
#define KFEAT 7128
#define FPC 112                 // padded features per channel (108 real + 4 zero)
#define KF2 (CCH * FPC)         // 7392
#define KP2 7424                // KF2 padded to x32
#define NCH2 (KP2 / 8)          // 928 chunk-rows in feats2
#define ROWE (BSZ * 8)          // f16 elements per chunk-row (32768)
#define LC (LLEN * CCH)
#define XROWS 106               // xB rows per channel: l+3 for l in [-3, 102] (zero halo)
#define CWS 640                 // packed-weight stride per channel (u32)
#define OSTR 49                 // obuf row stride in u32 (48 data + 1 pad)

// ---------------------------------------------------------------- async G->LDS
typedef __attribute__((address_space(1))) const u32 gu32;
typedef __attribute__((address_space(3))) u32 lu32;

__device__ __forceinline__ void gload_lds16(const void* g, void* l) {
    __builtin_amdgcn_global_load_lds((gu32*)g, (lu32*)l, 16, 0, 0);
}

// ---------------------------------------------------------------- h2 helpers
__device__ __forceinline__ h2  uh(u32 v) { return __builtin_bit_cast(h2, v); }
__device__ __forceinline__ u32 hu(h2 v)  { return __builtin_bit_cast(u32, v); }
__device__ __forceinline__ h2  pkfma(h2 a, h2 b, h2 c) { return __builtin_elementwise_fma(a, b, c); }
__device__ __forceinline__ h2  pkmax0(h2 a) { h2 z = (h2)(_Float16)0.f; return __builtin_elementwise_max(a, z); }
__device__ __forceinline__ u32 dupf(float v) { _Float16 x = (_Float16)v; return hu((h2){x, x}); }
__device__ __forceinline__ u32 pk2f(float a, float b) { return hu((h2){(_Float16)a, (_Float16)b}); }

// ---------------------------------------------------------------- transpose+pack (batch pairs)
// x [B][L][C] f32 -> xB[c][l+3][p] u32 = (f16 x[2p][l][c], f16 x[2p+1][l][c])
__global__ __launch_bounds__(256) void xpose_pack(const float* __restrict__ x,
                                                  u32* __restrict__ xB) {
    __shared__ float tile[64][133];     // 64 batches x (2 l x 66 c), pad -> conflict-light
    const int lp = blockIdx.x;          // l = 2*lp, 2*lp+1
    const int b0 = blockIdx.y * 64;
    const int tid = threadIdx.x;
    const float* src = x + (size_t)b0 * LC + (size_t)(2 * lp) * CCH;
#pragma unroll
    for (int i = 0; i < 33; ++i) {      // 64 rows x 132 cols = 33 x 256
        int f = i * 256 + tid;
        int bi = f / 132, j = f - bi * 132;
        tile[bi][j] = src[(size_t)bi * LC + j];
    }
    __syncthreads();
    const int pp = tid & 31, grp = tid >> 5;   // 8 groups of 32 pair-lanes
    for (int l2 = 0; l2 < 2; ++l2)
        for (int c = grp; c < CCH; c += 8) {
            u32 v = pk2f(tile[2 * pp][l2 * 66 + c], tile[2 * pp + 1][l2 * 66 + c]);
            xB[((size_t)c * XROWS + (2 * lp + l2 + 3)) * NPAIR + (b0 >> 1) + pp] = v;
        }
}

// zero halo rows: l+3 in {0,1,2, 103,104,105}
__global__ __launch_bounds__(256) void zero_halo_xB(u32* __restrict__ xB) {
    const int c = blockIdx.x;
    const int i = blockIdx.y * 256 + threadIdx.x;   // [0, 3072)
    size_t base = (size_t)c * (XROWS * NPAIR);
    size_t off = (i < 1536) ? (size_t)i * 4
                            : (size_t)(103 * NPAIR) + (size_t)(i - 1536) * 4;
    *(u32x4*)(xB + base + off) = (u32x4){0u, 0u, 0u, 0u};
}

// ---------------------------------------------------------------- packed weights (dup'd, pool-folded)
// per-c layout (u32): high @0:   w1[56] b1[8] w2*0.5[224] b2[4] w3*0.25[112] b3*0.5[4]   (408)
//                     low  @408: w1[24] b1[8] w2*0.5[96]  b2[4] w3*0.25[48]  b3*0.5[4]   (184)
__global__ __launch_bounds__(64) void prep_w(
    const float* __restrict__ hw1, const float* __restrict__ hb1,
    const float* __restrict__ hw2, const float* __restrict__ hb2,
    const float* __restrict__ hw3, const float* __restrict__ hb3,
    const float* __restrict__ lw1, const float* __restrict__ lb1,
    const float* __restrict__ lw2, const float* __restrict__ lb2,
    const float* __restrict__ lw3, const float* __restrict__ lb3,
    u32* __restrict__ wpk) {
    const int c = blockIdx.x, t = threadIdx.x;
    u32* wb = wpk + c * CWS;
    for (int i = t; i < 56; i += 64)  wb[i]       = dupf(hw1[c * 56 + i]);
    if (t < 8)                        wb[56 + t]  = dupf(hb1[c * 8 + t]);
    for (int i = t; i < 224; i += 64) wb[64 + i]  = dupf(0.5f * hw2[c * 224 + i]);
    if (t < 4)                        wb[288 + t] = dupf(hb2[c * 4 + t]);
    for (int i = t; i < 112; i += 64) wb[292 + i] = dupf(0.25f * hw3[c * 112 + i]);
    if (t < 4)                        wb[404 + t] = dupf(0.5f * hb3[c * 4 + t]);
    for (int i = t; i < 24; i += 64)  wb[408 + i] = dupf(lw1[c * 24 + i]);
    if (t < 8)                        wb[432 + t] = dupf(lb1[c * 8 + t]);
    for (int i = t; i < 96; i += 64)  wb[440 + i] = dupf(0.5f * lw2[c * 96 + i]);
    if (t < 4)                        wb[536 + t] = dupf(lb2[c * 4 + t]);
    for (int i = t; i < 48; i += 64)  wb[540 + i] = dupf(0.25f * lw3[c * 48 + i]);
    if (t < 4)                        wb[588 + t] = dupf(0.5f * lb3[c * 4 + t]);
}

// ---------------------------------------------------------------- feature pipeline (batch-packed)
// Each thread: 2 batch elements, full branch. x[l] at xg[(l+3)*NPAIR].
// All pool 0.5 factors folded into w2/w3/b3 (exact pow2) -> rings hold UNSCALED
// relu-pair sums; every op is a full-register v_pk_*.
template<int K>
__device__ __forceinline__ void run_branch_b(const u32* __restrict__ xg,
                                             const u32* __restrict__ wb,
                                             u32* __restrict__ orow) {
    constexpr int P = K / 2;
    constexpr int XW = K + 3;
    const u32* w1 = wb;
    const u32* b1 = wb + 8 * K;
    const u32* w2 = b1 + 8;
    const u32* b2 = w2 + 32 * K;
    const u32* w3 = b2 + 4;
    const u32* b3 = w3 + 16 * K;

    u32 X[XW];                 // sliding x window
    u32 R1[8][K + 1];          // h1 ring: relu(y1[2u])+relu(y1[2u+1])
    u32 R3[4][K];              // h2 ring: relu(y2[2s])+relu(y2[2s+1])
#pragma unroll
    for (int ic = 0; ic < 8; ++ic)
#pragma unroll
        for (int j = 0; j <= K; ++j) R1[ic][j] = 0u;
#pragma unroll
    for (int oc = 0; oc < 4; ++oc)
#pragma unroll
        for (int j = 0; j < K; ++j) R3[oc][j] = 0u;

    // invariant before producing h1[u]: X[j] = x[2u - P - 2 + j]
#pragma unroll
    for (int j = 0; j < XW; ++j)
        X[j] = (j + 1 - P >= 0) ? xg[(size_t)(j + 1 - P) * NPAIR] : 0u;

    auto produce_eval = [&](int u, u32* nh) {
        if (u < 50) {
#pragma unroll
            for (int ic = 0; ic < 8; ++ic) {
                h2 A = uh(b1[ic]);
                h2 B = A;
#pragma unroll
                for (int k = 0; k < K; ++k) {
                    h2 w = uh(w1[ic * K + k]);
                    A = pkfma(w, uh(X[2 + k]), A);
                    B = pkfma(w, uh(X[3 + k]), B);
                }
                nh[ic] = hu(pkmax0(A) + pkmax0(B));
            }
        } else {
#pragma unroll
            for (int ic = 0; ic < 8; ++ic) nh[ic] = 0u;
        }
        // slide window by 2, load 2 (overreads past row 105 are masked & land in wpk)
#pragma unroll
        for (int j = 0; j < XW - 2; ++j) X[j] = X[j + 2];
        const int r0 = 2 * u + K - P + 4;
        X[XW - 2] = xg[(size_t)r0 * NPAIR];
        X[XW - 1] = xg[(size_t)(r0 + 1) * NPAIR];
    };

    h2 Q[4], prevO[4];
#pragma unroll
    for (int oc = 0; oc < 4; ++oc) { Q[oc] = (h2)(_Float16)0.f; prevO[oc] = (h2)(_Float16)0.f; }

    auto conv3p = [&](int p) {
        h2 Y3[4];
#pragma unroll
        for (int oc = 0; oc < 4; ++oc) Y3[oc] = uh(b3[oc]);
#pragma unroll
        for (int ic = 0; ic < 4; ++ic)
#pragma unroll
            for (int k = 0; k < K; ++k) {
                h2 r = uh(R3[ic][k]);
#pragma unroll
                for (int oc = 0; oc < 4; ++oc)
                    Y3[oc] = pkfma(uh(w3[(oc * 4 + ic) * K + k]), r, Y3[oc]);
            }
        if ((p & 1) == 0) {
#pragma unroll
            for (int oc = 0; oc < 4; ++oc) Q[oc] = pkmax0(Y3[oc]);
        } else {
            const int w = p >> 1;          // out[w] = Q + relu(Y3)  (0.5 folded)
#pragma unroll
            for (int oc = 0; oc < 4; ++oc) {
                h2 O = Q[oc] + pkmax0(Y3[oc]);
                if ((w & 1) == 0) prevO[oc] = O;
                else {                     // feature pair (w-1, w) -> per-batch u32
                    orow[oc * 6 + (w >> 1)]      = hu((h2){prevO[oc].x, O.x});
                    orow[24 + oc * 6 + (w >> 1)] = hu((h2){prevO[oc].y, O.y});
                }
            }
        }
    };

    // prologue: h1[0..P-1] (ring pre-fill; negatives stay zero)
#pragma unroll
    for (int u = 0; u < P; ++u) {
        u32 nh[8];
        produce_eval(u, nh);
#pragma unroll
        for (int ic = 0; ic < 8; ++ic) {
#pragma unroll
            for (int j = 0; j < K; ++j) R1[ic][j] = R1[ic][j + 1];
            R1[ic][K] = nh[ic];
        }
    }

#pragma unroll 1
    for (int s2 = 0; s2 < 25; ++s2) {
        u32 nhA[8], nhB[8];
        produce_eval(2 * s2 + P, nhA);
        produce_eval(2 * s2 + P + 1, nhB);
#pragma unroll
        for (int ic = 0; ic < 8; ++ic) {   // ring shift by 2, append
#pragma unroll
            for (int j = 0; j < K - 1; ++j) R1[ic][j] = R1[ic][j + 2];
            R1[ic][K - 1] = nhA[ic];
            R1[ic][K]     = nhB[ic];
        }
        // conv2 at s = 2*s2, 2*s2+1 (w2 pre-halved)
        h2 Y0[4], Y1[4];
#pragma unroll
        for (int oc = 0; oc < 4; ++oc) { Y0[oc] = uh(b2[oc]); Y1[oc] = Y0[oc]; }
#pragma unroll
        for (int ic = 0; ic < 8; ++ic)
#pragma unroll
            for (int k = 0; k < K; ++k) {
                h2 r0 = uh(R1[ic][k]);
                h2 r1 = uh(R1[ic][k + 1]);
#pragma unroll
                for (int oc = 0; oc < 4; ++oc) {
                    h2 w = uh(w2[(oc * 8 + ic) * K + k]);
                    Y0[oc] = pkfma(w, r0, Y0[oc]);
                    Y1[oc] = pkfma(w, r1, Y1[oc]);
                }
            }
#pragma unroll
        for (int oc = 0; oc < 4; ++oc) {   // pool2 (unscaled sum) -> R3 push
            h2 d = pkmax0(Y0[oc]) + pkmax0(Y1[oc]);
#pragma unroll
            for (int j = 0; j < K - 1; ++j) R3[oc][j] = R3[oc][j + 1];
            R3[oc][K - 1] = hu(d);
        }
        if (s2 >= P) conv3p(s2 - P);
    }
    // tail: remaining conv3 positions with zero-padded h2 (high branch only)
#pragma unroll
    for (int e = 0; e < P - 1; ++e) {
#pragma unroll
        for (int oc = 0; oc < 4; ++oc) {
#pragma unroll
            for (int j = 0; j < K - 1; ++j) R3[oc][j] = R3[oc][j + 1];
            R3[oc][K - 1] = 0u;
        }
        conv3p(25 - P + e);
    }
}

// feats2 blocked layout unchanged: element (b, k = c*112 + f) at
//   feats2[(c*14 + (f>>3)) * ROWE + b*8 + (f&7)]
// blockIdx.z: 0 = high branch (chunks 0..5), 1 = low branch + residual (6..13)
__global__ __launch_bounds__(256, 3) void feats_kernel(
    const u32* __restrict__ xB, const u32* __restrict__ wpk,
    f16* __restrict__ feats2) {
    __shared__ u32 obufw[256 * OSTR];   // 50,176 B -> 3 blocks/CU
    const int c = blockIdx.x;
    const int tid = threadIdx.x;
    const int pr = blockIdx.y * 256 + tid;       // batch pair (batches 2pr, 2pr+1)

    const u32* xg = xB + (size_t)c * (XROWS * NPAIR) + pr;
    const u32* wb = wpk + c * CWS;
    u32* orow = obufw + tid * OSTR;              // [0..23]=batch0 words, [24..47]=batch1
    u32* dst = (u32*)feats2 + (size_t)c * 14 * (ROWE / 2) + (size_t)pr * 8;

    if (blockIdx.z == 0) {
        run_branch_b<7>(xg, wb, orow);
        u32 v0[24], v1[24];
#pragma unroll
        for (int j = 0; j < 24; ++j) { v0[j] = orow[j]; v1[j] = orow[24 + j]; }  // same-thread RAW
#pragma unroll
        for (int ch = 0; ch < 6; ++ch) {
            *(u32x4*)(dst + (size_t)ch * (ROWE / 2)) =
                (u32x4){v0[ch * 4], v0[ch * 4 + 1], v0[ch * 4 + 2], v0[ch * 4 + 3]};
            *(u32x4*)(dst + (size_t)ch * (ROWE / 2) + 4) =
                (u32x4){v1[ch * 4], v1[ch * 4 + 1], v1[ch * 4 + 2], v1[ch * 4 + 3]};
        }
    } else {
        run_branch_b<3>(xg, wb + 408, orow);
        u32 v0[24], v1[24];
#pragma unroll
        for (int j = 0; j < 24; ++j) { v0[j] = orow[j]; v1[j] = orow[24 + j]; }
#pragma unroll
        for (int ch = 0; ch < 6; ++ch) {
            *(u32x4*)(dst + (size_t)(6 + ch) * (ROWE / 2)) =
                (u32x4){v0[ch * 4], v0[ch * 4 + 1], v0[ch * 4 + 2], v0[ch * 4 + 3]};
            *(u32x4*)(dst + (size_t)(6 + ch) * (ROWE / 2) + 4) =
                (u32x4){v1[ch * 4], v1[ch * 4 + 1], v1[ch * 4 + 2], v1[ch * 4 + 3]};
        }
        // residual pooling -> chunks 12..13
        u32 rr0[6], rr1[6];
        h2 prevR = (h2)(_Float16)0.f;
#pragma unroll
        for (int w = 0; w < 12; ++w) {
            h2 a0 = uh(xg[(size_t)(8 * w + 3) * NPAIR]) + uh(xg[(size_t)(8 * w + 4) * NPAIR]);
            h2 a1 = uh(xg[(size_t)(8 * w + 5) * NPAIR]) + uh(xg[(size_t)(8 * w + 6) * NPAIR]);
            h2 a2 = uh(xg[(size_t)(8 * w + 7) * NPAIR]) + uh(xg[(size_t)(8 * w + 8) * NPAIR]);
            h2 a3 = uh(xg[(size_t)(8 * w + 9) * NPAIR]) + uh(xg[(size_t)(8 * w + 10) * NPAIR]);
            h2 s = ((a0 + a1) + (a2 + a3)) * (h2)(_Float16)0.125f;
            if ((w & 1) == 0) prevR = s;
            else { rr0[w >> 1] = hu((h2){prevR.x, s.x}); rr1[w >> 1] = hu((h2){prevR.y, s.y}); }
        }
        *(u32x4*)(dst + (size_t)12 * (ROWE / 2))     = (u32x4){rr0[0], rr0[1], rr0[2], rr0[3]};
        *(u32x4*)(dst + (size_t)12 * (ROWE / 2) + 4) = (u32x4){rr1[0], rr1[1], rr1[2], rr1[3]};
        *(u32x4*)(dst + (size_t)13 * (ROWE / 2))     = (u32x4){rr0[4], rr0[5], 0u, 0u};
        *(u32x4*)(dst + (size_t)13 * (ROWE / 2) + 4) = (u32x4){rr1[4], rr1[5], 0u, 0u};
    }
}

// zero the pad chunk-rows (k = 7392..7423 -> rows 924..927)
__global__ void zero_pad2(f16* __restrict__ feats2) {
    int idx = blockIdx.x * 256 + threadIdx.x;
    u32* dst = (u32*)(feats2 + (size_t)(CCH * 14) * ROWE);
    if (idx < (4 * ROWE * 2) / 16)
        *(u32x4*)(dst + idx * 4) = (u32x4){0u, 0u, 0u, 0u};
}

// convert fw1 (1936 x 7128 f32) -> padded f16 (2048 x 7424) with per-c pad
__global__ void cvt_fw1(const float* __restrict__ fw1, f16* __restrict__ dst) {
    int n = blockIdx.y;
    int kp = blockIdx.x * 256 + threadIdx.x;
    if (kp >= KP2) return;
    int c2 = kp / FPC, f = kp - c2 * FPC;
    float v = 0.f;
    if (n < NOUT && kp < KF2 && f < 108)
        v = fw1[(size_t)n * KFEAT + c2 * 108 + f];
    dst[(size_t)n * KP2 + kp] = (f16)v;
}

// ---------------------------------------------------------------- FC1 GEMM
// BM=64, BN=128 -> grid (64,16) = 1024 blocks = 4 blocks/CU (R9: 512 blocks =
// 2/CU was the bottleneck; m102 shape curve says blocks/CU dominates).
__global__ __launch_bounds__(256, 4) void fc1_gemm(
    const f16* __restrict__ A, const f16* __restrict__ Bw,
    const float* __restrict__ fb1, f16* __restrict__ H) {
    __shared__ f16 lds_a[64 * 32];      // 4 KB
    __shared__ f16 lds_b[128 * 32];     // 8 KB
    const int tid = threadIdx.x;
    const int bm = blockIdx.x;
    const int bn = blockIdx.y;
    const int wid = tid >> 6, lane = tid & 63;
    const int wm = wid >> 1, wn = wid & 1;

    f32x4 acc[2][4];
#pragma unroll
    for (int i = 0; i < 2; ++i)
#pragma unroll
        for (int j = 0; j < 4; ++j) acc[i][j] = (f32x4){0.f, 0.f, 0.f, 0.f};

    const f16* Bbase = Bw + (size_t)bn * 128 * KP2;
    const int l15 = lane & 15, lhi = lane >> 4;

    const int arow = tid >> 2, akc = tid & 3;
    const int brow0 = tid >> 2, bkc0 = tid & 3;
    const int brow1 = (256 + tid) >> 2, bkc1 = tid & 3;

    for (int k0 = 0; k0 < KP2; k0 += 32) {
        __syncthreads();
        gload_lds16(A + (size_t)((k0 >> 3) + akc) * ROWE + (size_t)(bm * 64 + arow) * 8,
                    (char*)lds_a + tid * 16);
        gload_lds16(Bbase + (size_t)brow0 * KP2 + k0 + bkc0 * 8, (char*)lds_b + tid * 16);
        gload_lds16(Bbase + (size_t)brow1 * KP2 + k0 + bkc1 * 8, (char*)lds_b + (256 + tid) * 16);
        __syncthreads();

        f16x8 af[2], bf[4];
#pragma unroll
        for (int i = 0; i < 2; ++i) {
            int m = wm * 32 + i * 16 + l15;
            af[i] = *(const f16x8*)(lds_a + m * 32 + lhi * 8);
        }
#pragma unroll
        for (int j = 0; j < 4; ++j) {
            int n = wn * 64 + j * 16 + l15;
            bf[j] = *(const f16x8*)(lds_b + n * 32 + lhi * 8);
        }
#pragma unroll
        for (int i = 0; i < 2; ++i)
#pragma unroll
            for (int j = 0; j < 4; ++j)
                acc[i][j] = __builtin_amdgcn_mfma_f32_16x16x32_f16(af[i], bf[j], acc[i][j], 0, 0, 0);
    }

#pragma unroll
    for (int i = 0; i < 2; ++i) {
#pragma unroll
        for (int j = 0; j < 4; ++j) {
            int n = bn * 128 + wn * 64 + j * 16 + l15;
            float bias = (n < NOUT) ? fb1[n] : 0.f;
#pragma unroll
            for (int r = 0; r < 4; ++r) {
                int m = bm * 64 + wm * 32 + i * 16 + lhi * 4 + r;
                float v = acc[i][j][r] + bias;
                H[(size_t)m * NPAD + n] = (f16)fmaxf(v, 0.f);
            }
        }
    }
}

// ---------------------------------------------------------------- FC2
__global__ __launch_bounds__(64) void fc2_kernel(const f16* __restrict__ H,
                                                 const float* __restrict__ fw2,
                                                 const float* __restrict__ fb2,
                                                 float* __restrict__ out) {
    const int b = blockIdx.x;
    const int t = threadIdx.x;
    const f16* hb = H + (size_t)b * NPAD;
    float acc[14];
#pragma unroll
    for (int o = 0; o < 14; ++o) acc[o] = 0.f;
    for (int k = t; k < NOUT; k += 64) {
        float hv = (float)hb[k];
#pragma unroll
        for (int o = 0; o < 14; ++o) acc[o] += hv * fw2[o * NOUT + k];
    }
#pragma unroll
    for (int o = 0; o < 14; ++o) {
        float v = acc[o];
#pragma unroll
        for (int off = 32; off > 0; off >>= 1) v += __shfl_down(v, off, 64);
        if (t == 0) out[b * 14 + o] = v + fb2[o];
    }
}

// ---------------------------------------------------------------- launcher
extern "C" void kernel_launch(void* const* d_in, const int* in_sizes, int n_in,
                              void* d_out, int out_size, void* d_ws, size_t ws_size,
                              hipStream_t stream) {
    const float* x   = (const float*)d_in[0];
    const float* hw1 = (const float*)d_in[1];
    const float* hb1 = (const float*)d_in[2];
    const float* hw2 = (const float*)d_in[3];
    const float* hb2 = (const float*)d_in[4];
    const float* hw3 = (const float*)d_in[5];
    const float* hb3 = (const float*)d_in[6];
    const float* lw1 = (const float*)d_in[7];
    const float* lb1 = (const float*)d_in[8];
    const float* lw2 = (const float*)d_in[9];
    const float* lb2 = (const float*)d_in[10];
    const float* lw3 = (const float*)d_in[11];
    const float* lb3 = (const float*)d_in[12];
    const float* fw1 = (const float*)d_in[13];
    const float* fb1 = (const float*)d_in[14];
    const float* fw2 = (const float*)d_in[15];
    const float* fb2 = (const float*)d_in[16];

    // workspace (byte offsets; aliases exploit disjoint lifetimes):
    // [0, 60.8M)           feats2
    // [60.8M, 77.6M)       h f16 (16.8M)
    // [77.6M, 134.9M)      xB (57.3M) -> later fw1H (30.4M) aliases its head
    // [134.9M, 135.1M)     wpk (also absorbs feats' masked tail overreads)
    char* wsb = (char*)d_ws;
    f16*  feats2 = (f16*)wsb;
    f16*  h      = (f16*)(wsb + 60817408);
    char* reg3   = wsb + 77594624;
    u32*  xB     = (u32*)reg3;
    f16*  fw1H   = (f16*)reg3;                               // aliases xB (after feats)
    u32*  wpk    = (u32*)(reg3 + (size_t)CCH * XROWS * NPAIR * 4);

    xpose_pack<<<dim3(50, BSZ / 64), 256, 0, stream>>>(x, xB);
    zero_halo_xB<<<dim3(CCH, 12), 256, 0, stream>>>(xB);
    prep_w<<<dim3(CCH), 64, 0, stream>>>(hw1, hb1, hw2, hb2, hw3, hb3,
                                         lw1, lb1, lw2, lb2, lw3, lb3, wpk);
    feats_kernel<<<dim3(CCH, NPAIR / 256, 2), 256, 0, stream>>>(xB, wpk, feats2);
    zero_pad2<<<dim3(64), 256, 0, stream>>>(feats2);
    cvt_fw1<<<dim3((KP2 + 255) / 256, NPAD), 256, 0, stream>>>(fw1, fw1H);  // xB dead now
    fc1_gemm<<<dim3(BSZ / 64, NPAD / 128), 256, 0, stream>>>(feats2, fw1H, fb1, h);
    fc2_kernel<<<dim3(BSZ), 64, 0, stream>>>(h, fw2, fb2, (float*)d_out);
}